// Round 4
// baseline (228.433 us; speedup 1.0000x reference)
//
#include <hip/hip_runtime.h>

#define NE 8
#define DIM 1024
#define ALPHA_C 10.0f

typedef float f32x4 __attribute__((ext_vector_type(4)));
typedef float f32x2 __attribute__((ext_vector_type(2)));

// 4 lanes per row, 16 rows per wave. W in LDS read via broadcast addresses.
// x read with NON-TEMPORAL loads (no cache allocation for the 512 MB stream).
__global__ __launch_bounds__(512, 4) void topk_gating_kernel(
    const float* __restrict__ x,
    const float* __restrict__ gw,
    const float* __restrict__ gb,
    float* __restrict__ out,
    int nrows)
{
    __shared__ float wlds[NE * DIM];   // 32 KiB

    const int tid = threadIdx.x;

    // Stage W into LDS, coalesced: 2048 float4 / 512 thr = 4 each (normal loads; W is reused)
    {
        const float4* src = (const float4*)gw;
        float4* dst = (float4*)wlds;
        #pragma unroll
        for (int i = 0; i < 4; ++i)
            dst[tid + i * 512] = src[tid + i * 512];
    }
    float bias[NE];
    #pragma unroll
    for (int e = 0; e < NE; ++e) bias[e] = gb[e];
    __syncthreads();

    const int lane = tid & 63;
    const int g = lane >> 2;          // row-within-group-of-16
    const int s = lane & 3;           // sub-lane within row
    const int wid = (blockIdx.x * blockDim.x + tid) >> 6;
    const int nwaves = (gridDim.x * blockDim.x) >> 6;

    const f32x4* x4 = (const f32x4*)x;
    const f32x4* w4 = (const f32x4*)wlds;

    for (int base = wid * 16; base < nrows; base += nwaves * 16) {
        const int row = base + g;
        const bool valid = row < nrows;
        const size_t xoff = (size_t)row * (DIM / 4) + s;

        float acc[NE] = {0.f, 0.f, 0.f, 0.f, 0.f, 0.f, 0.f, 0.f};
        if (valid) {
            #pragma unroll 2
            for (int j = 0; j < 64; ++j) {
                // lanes of a group read 64 B contiguous; NT: bypass cache allocation
                f32x4 xv = __builtin_nontemporal_load(&x4[xoff + j * 4]);
                #pragma unroll
                for (int e = 0; e < NE; ++e) {
                    // only 4 unique addresses per wave instr -> broadcast, cheap
                    f32x4 wv = w4[e * (DIM / 4) + j * 4 + s];
                    acc[e] += xv.x * wv.x + xv.y * wv.y + xv.z * wv.z + xv.w * wv.w;
                }
            }
        }

        // Reduce across the 4 lanes of each group; all 4 end with full sums.
        #pragma unroll
        for (int e = 0; e < NE; ++e) {
            float v = acc[e];
            v += __shfl_xor(v, 1);
            v += __shfl_xor(v, 2);
            acc[e] = v + bias[e];
        }

        // ---- epilogue (redundant across the 4 lanes of a row) ----
        // max and 2nd-largest (duplicate-preserving == kthvalue semantics)
        float m1 = -INFINITY, m2 = -INFINITY;
        #pragma unroll
        for (int e = 0; e < NE; ++e) {
            float v = acc[e];
            float nm2 = fmaxf(m2, fminf(m1, v));
            m1 = fmaxf(m1, v);
            m2 = nm2;
        }

        // softmax of raw logits
        float ex[NE];
        float sum = 0.f;
        #pragma unroll
        for (int e = 0; e < NE; ++e) {
            ex[e] = __expf(acc[e] - m1);
            sum += ex[e];
        }
        float inv = 1.f / sum;

        // decomposition: (l < kth) -> ALPHA*log1p(s), else ALPHA*(exp(s)-1)
        float o[NE];
        #pragma unroll
        for (int e = 0; e < NE; ++e) {
            float sft = ex[e] * inv;
            float topv = ALPHA_C * (__expf(sft) - 1.f);
            float lowv = ALPHA_C * __logf(1.f + sft);
            o[e] = (acc[e] >= m2) ? topv : lowv;
        }

        // final softmax
        float om = o[0];
        #pragma unroll
        for (int e = 1; e < NE; ++e) om = fmaxf(om, o[e]);
        float oex[NE];
        float osum = 0.f;
        #pragma unroll
        for (int e = 0; e < NE; ++e) {
            oex[e] = __expf(o[e] - om);
            osum += oex[e];
        }
        float oinv = 1.f / osum;

        // lane s writes gates[2s], gates[2s+1] as float2 (coalesced per group)
        float ga = oex[0] * oinv;
        float gbv = oex[1] * oinv;
        #pragma unroll
        for (int e = 1; e < 4; ++e) {
            float ca = oex[2 * e] * oinv;
            float cb = oex[2 * e + 1] * oinv;
            ga  = (s == e) ? ca : ga;
            gbv = (s == e) ? cb : gbv;
        }
        if (valid) {
            f32x2 o2;
            o2.x = ga; o2.y = gbv;
            __builtin_nontemporal_store(o2, &((f32x2*)out)[(size_t)row * 4 + s]);
        }
    }
}

extern "C" void kernel_launch(void* const* d_in, const int* in_sizes, int n_in,
                              void* d_out, int out_size, void* d_ws, size_t ws_size,
                              hipStream_t stream) {
    const float* x  = (const float*)d_in[0];
    const float* gw = (const float*)d_in[1];
    const float* gb = (const float*)d_in[2];
    float* out = (float*)d_out;
    const int nrows = in_sizes[0] / DIM;

    const int block = 512;   // 8 waves/block, 32 KiB LDS -> 4 blocks/CU
    const int grid = 1024;   // 8192 waves == 8192 groups of 16 rows at N=131072
    topk_gating_kernel<<<grid, block, 0, stream>>>(x, gw, gb, out, nrows);
}

// Round 5
// 135.725 us; speedup vs baseline: 1.6831x; 1.6831x over previous
//
#include <hip/hip_runtime.h>

#define NE 8
#define DIM 1024
#define ALPHA_C 10.0f

typedef float f32x4 __attribute__((ext_vector_type(4)));

// 8 lanes per row, 8 rows per wave. Every x wave-load segment = one full
// 128-B cache line (copy-benchmark granularity). W in LDS, broadcast reads.
__global__ __launch_bounds__(256, 5) void topk_gating_kernel(
    const float* __restrict__ x,
    const float* __restrict__ gw,
    const float* __restrict__ gb,
    float* __restrict__ out,
    int nrows)
{
    __shared__ float wlds[NE * DIM];   // 32 KiB

    const int tid = threadIdx.x;

    // Stage W into LDS, coalesced: 2048 float4 / 256 thr = 8 each
    {
        const float4* src = (const float4*)gw;
        float4* dst = (float4*)wlds;
        #pragma unroll
        for (int i = 0; i < 8; ++i)
            dst[tid + i * 256] = src[tid + i * 256];
    }
    float bias[NE];
    #pragma unroll
    for (int e = 0; e < NE; ++e) bias[e] = gb[e];
    __syncthreads();

    const int lane = tid & 63;
    const int g = lane >> 3;          // row-within-group-of-8
    const int s = lane & 7;           // sub-lane within row (128-B line index)
    const int wid = (blockIdx.x * blockDim.x + tid) >> 6;
    const int nwaves = (gridDim.x * blockDim.x) >> 6;

    const f32x4* x4 = (const f32x4*)x;
    const f32x4* w4 = (const f32x4*)wlds;

    for (int base = wid * 8; base < nrows; base += nwaves * 8) {
        const int row = base + g;
        const bool valid = row < nrows;
        const size_t xoff = (size_t)row * (DIM / 4) + s;

        float acc[NE] = {0.f, 0.f, 0.f, 0.f, 0.f, 0.f, 0.f, 0.f};
        if (valid) {
            // 32 j-steps; each wave-instruction reads 8 rows x 128 B = 8 full lines
            #pragma unroll 4
            for (int j = 0; j < 32; ++j) {
                f32x4 xv = x4[xoff + (size_t)j * 8];
                #pragma unroll
                for (int e = 0; e < NE; ++e) {
                    // 8 unique LDS addresses per wave instr -> broadcast, cheap
                    f32x4 wv = w4[e * (DIM / 4) + j * 8 + s];
                    acc[e] += xv.x * wv.x + xv.y * wv.y + xv.z * wv.z + xv.w * wv.w;
                }
            }
        }

        // Allgather butterfly over the 8 lanes of each row: afterwards every
        // lane of the group holds all 8 complete logits.
        #pragma unroll
        for (int e = 0; e < NE; ++e) {
            float v = acc[e];
            v += __shfl_xor(v, 1);
            v += __shfl_xor(v, 2);
            v += __shfl_xor(v, 4);
            acc[e] = v + bias[e];
        }

        // ---- epilogue (redundant across the 8 lanes of a row) ----
        // max and 2nd-largest (duplicate-preserving == kthvalue semantics)
        float m1 = -INFINITY, m2 = -INFINITY;
        #pragma unroll
        for (int e = 0; e < NE; ++e) {
            float v = acc[e];
            float nm2 = fmaxf(m2, fminf(m1, v));
            m1 = fmaxf(m1, v);
            m2 = nm2;
        }

        // softmax of raw logits
        float ex[NE];
        float sum = 0.f;
        #pragma unroll
        for (int e = 0; e < NE; ++e) {
            ex[e] = __expf(acc[e] - m1);
            sum += ex[e];
        }
        float inv = 1.f / sum;

        // decomposition: (l < kth) -> ALPHA*log1p(s), else ALPHA*(exp(s)-1)
        float o[NE];
        #pragma unroll
        for (int e = 0; e < NE; ++e) {
            float sft = ex[e] * inv;
            float topv = ALPHA_C * (__expf(sft) - 1.f);
            float lowv = ALPHA_C * __logf(1.f + sft);
            o[e] = (acc[e] >= m2) ? topv : lowv;
        }

        // final softmax
        float om = o[0];
        #pragma unroll
        for (int e = 1; e < NE; ++e) om = fmaxf(om, o[e]);
        float oex[NE];
        float osum = 0.f;
        #pragma unroll
        for (int e = 0; e < NE; ++e) {
            oex[e] = __expf(o[e] - om);
            osum += oex[e];
        }
        float oinv = 1.f / osum;

        // lane s writes gates[s]; compile-time-index select chain (no scratch)
        float gsel = oex[0] * oinv;
        #pragma unroll
        for (int e = 1; e < NE; ++e) {
            float ge = oex[e] * oinv;
            gsel = (s == e) ? ge : gsel;
        }
        if (valid) out[(size_t)row * NE + s] = gsel;
    }
}

extern "C" void kernel_launch(void* const* d_in, const int* in_sizes, int n_in,
                              void* d_out, int out_size, void* d_ws, size_t ws_size,
                              hipStream_t stream) {
    const float* x  = (const float*)d_in[0];
    const float* gw = (const float*)d_in[1];
    const float* gb = (const float*)d_in[2];
    float* out = (float*)d_out;
    const int nrows = in_sizes[0] / DIM;

    const int block = 256;   // 4 waves/block, 16 KiB LDS
    const int grid = 2048;   // 8192 waves x 8 rows = 65536 rows/sweep -> 2 iters
    topk_gating_kernel<<<grid, block, 0, stream>>>(x, gw, gb, out, nrows);
}

// Round 6
// 128.973 us; speedup vs baseline: 1.7712x; 1.0524x over previous
//
#include <hip/hip_runtime.h>

#define NE 8
#define DIM 1024
#define ALPHA_C 10.0f

typedef float f32x4 __attribute__((ext_vector_type(4)));

// 8 lanes per row, 8 rows per wave. Every x wave-load segment = one full
// 128-B cache line. x loads NON-TEMPORAL (no L2/L3 allocation; full-line
// segments mean no overfetch). W in LDS, broadcast reads.
__global__ __launch_bounds__(256, 5) void topk_gating_kernel(
    const float* __restrict__ x,
    const float* __restrict__ gw,
    const float* __restrict__ gb,
    float* __restrict__ out,
    int nrows)
{
    __shared__ float wlds[NE * DIM];   // 32 KiB

    const int tid = threadIdx.x;

    // Stage W into LDS, coalesced: 2048 float4 / 256 thr = 8 each
    {
        const float4* src = (const float4*)gw;
        float4* dst = (float4*)wlds;
        #pragma unroll
        for (int i = 0; i < 8; ++i)
            dst[tid + i * 256] = src[tid + i * 256];
    }
    float bias[NE];
    #pragma unroll
    for (int e = 0; e < NE; ++e) bias[e] = gb[e];
    __syncthreads();

    const int lane = tid & 63;
    const int g = lane >> 3;          // row-within-group-of-8
    const int s = lane & 7;           // sub-lane within row (128-B line index)
    const int wid = (blockIdx.x * blockDim.x + tid) >> 6;
    const int nwaves = (gridDim.x * blockDim.x) >> 6;

    const f32x4* x4 = (const f32x4*)x;
    const f32x4* w4 = (const f32x4*)wlds;

    for (int base = wid * 8; base < nrows; base += nwaves * 8) {
        const int row = base + g;
        const bool valid = row < nrows;
        const size_t xoff = (size_t)row * (DIM / 4) + s;

        float acc[NE] = {0.f, 0.f, 0.f, 0.f, 0.f, 0.f, 0.f, 0.f};
        if (valid) {
            // 32 j-steps; each wave-instruction reads 8 rows x 128 B = 8 full lines
            #pragma unroll 4
            for (int j = 0; j < 32; ++j) {
                f32x4 xv = __builtin_nontemporal_load(&x4[xoff + (size_t)j * 8]);
                #pragma unroll
                for (int e = 0; e < NE; ++e) {
                    // 8 unique LDS addresses per wave instr -> broadcast, cheap
                    f32x4 wv = w4[e * (DIM / 4) + j * 8 + s];
                    acc[e] += xv.x * wv.x + xv.y * wv.y + xv.z * wv.z + xv.w * wv.w;
                }
            }
        }

        // Allgather butterfly over the 8 lanes of each row: afterwards every
        // lane of the group holds all 8 complete logits.
        #pragma unroll
        for (int e = 0; e < NE; ++e) {
            float v = acc[e];
            v += __shfl_xor(v, 1);
            v += __shfl_xor(v, 2);
            v += __shfl_xor(v, 4);
            acc[e] = v + bias[e];
        }

        // ---- epilogue (redundant across the 8 lanes of a row) ----
        // max and 2nd-largest (duplicate-preserving == kthvalue semantics)
        float m1 = -INFINITY, m2 = -INFINITY;
        #pragma unroll
        for (int e = 0; e < NE; ++e) {
            float v = acc[e];
            float nm2 = fmaxf(m2, fminf(m1, v));
            m1 = fmaxf(m1, v);
            m2 = nm2;
        }

        // softmax of raw logits
        float ex[NE];
        float sum = 0.f;
        #pragma unroll
        for (int e = 0; e < NE; ++e) {
            ex[e] = __expf(acc[e] - m1);
            sum += ex[e];
        }
        float inv = 1.f / sum;

        // decomposition: (l < kth) -> ALPHA*log1p(s), else ALPHA*(exp(s)-1)
        float o[NE];
        #pragma unroll
        for (int e = 0; e < NE; ++e) {
            float sft = ex[e] * inv;
            float topv = ALPHA_C * (__expf(sft) - 1.f);
            float lowv = ALPHA_C * __logf(1.f + sft);
            o[e] = (acc[e] >= m2) ? topv : lowv;
        }

        // final softmax
        float om = o[0];
        #pragma unroll
        for (int e = 1; e < NE; ++e) om = fmaxf(om, o[e]);
        float oex[NE];
        float osum = 0.f;
        #pragma unroll
        for (int e = 0; e < NE; ++e) {
            oex[e] = __expf(o[e] - om);
            osum += oex[e];
        }
        float oinv = 1.f / osum;

        // lane s writes gates[s]; compile-time-index select chain (no scratch)
        float gsel = oex[0] * oinv;
        #pragma unroll
        for (int e = 1; e < NE; ++e) {
            float ge = oex[e] * oinv;
            gsel = (s == e) ? ge : gsel;
        }
        if (valid) out[(size_t)row * NE + s] = gsel;
    }
}

extern "C" void kernel_launch(void* const* d_in, const int* in_sizes, int n_in,
                              void* d_out, int out_size, void* d_ws, size_t ws_size,
                              hipStream_t stream) {
    const float* x  = (const float*)d_in[0];
    const float* gw = (const float*)d_in[1];
    const float* gb = (const float*)d_in[2];
    float* out = (float*)d_out;
    const int nrows = in_sizes[0] / DIM;

    const int block = 256;   // 4 waves/block, 32 KiB LDS
    const int grid = 2048;   // 8192 waves x 8 rows = 65536 rows/sweep -> 2 iters
    topk_gating_kernel<<<grid, block, 0, stream>>>(x, gw, gb, out, nrows);
}